// Round 1
// baseline (706.184 us; speedup 1.0000x reference)
//
#include <hip/hip_runtime.h>
#include <hip/hip_bf16.h>

// PHM8Linear: out[t, j] = sum_k H[j,k] * x[t,k] + bias[j]
//   H[j,k] = sum_i A[i, j>>6, k>>6] * S[i, j&63, k&63]   (512x512, built in bf16)
//   M = 16*8192 = 131072, K = N = 512.
// Memory floor: 268 MB x-read + 268 MB out-write ~= 85 us @ 6.3 TB/s.
//
// LDS-free GEMM: the 16x16x32 bf16 MFMA A-fragment is 8 contiguous k-elements
// per lane = one aligned 32B slice of an x row -> load it straight from global
// (two dwordx4), convert to bf16 in-register. B (=H, 512 KB bf16) is
// L2-resident on every XCD -> load fragments straight from global too.
// No LDS => no barriers, no vmcnt(0) drains per K-step (deep MLP), no bank
// conflicts, and each x row is read by exactly one block => FETCH == 268 MB
// by construction (the old 4-column-block grid re-fetched x ~2x across XCDs).
//
// Block: 64 rows x all 512 cols, 512 threads = 8 waves (2M x 4N),
// wave tile 32x128 -> acc[2][8] f32x4 = 64 VGPR/lane.

#define MDIM (16 * 8192)
#define KD 512
#define ND 512
#define BM 64

typedef __attribute__((ext_vector_type(8))) short short8;
typedef __attribute__((ext_vector_type(4))) float f32x4;

__device__ __forceinline__ unsigned pack2_bf16(float x, float y) {
    union { __hip_bfloat162 h; unsigned u; } cv;
    cv.h = __float22bfloat162_rn(make_float2(x, y));
    return cv.u;
}

__device__ __forceinline__ short8 cvt_frag(f32x4 a, f32x4 b) {
    union { unsigned u[4]; short8 s; } r;
    r.u[0] = pack2_bf16(a.x, a.y);
    r.u[1] = pack2_bf16(a.z, a.w);
    r.u[2] = pack2_bf16(b.x, b.y);
    r.u[3] = pack2_bf16(b.z, b.w);
    return r.s;
}

// H[j*512 + k] = sum_i A[i*64 + (j>>6)*8 + (k>>6)] * S[i*4096 + (j&63)*64 + (k&63)]
__global__ void build_h(const float* __restrict__ A, const float* __restrict__ S,
                        __hip_bfloat16* __restrict__ H) {
    int idx = blockIdx.x * 256 + threadIdx.x;   // 0 .. 262143
    int j = idx >> 9, k = idx & 511;
    int a = j >> 6, b = j & 63, c = k >> 6, d = k & 63;
    float acc = 0.f;
#pragma unroll
    for (int i = 0; i < 8; ++i)
        acc += A[i * 64 + a * 8 + c] * S[i * 4096 + b * 64 + d];
    H[idx] = __float2bfloat16(acc);
}

__global__ __launch_bounds__(512)
void phm_gemm(const float* __restrict__ X, const __hip_bfloat16* __restrict__ Hm,
              const float* __restrict__ bias, float* __restrict__ out) {
    const int tid = threadIdx.x;
    const int wave = tid >> 6, lane = tid & 63;
    const int wm = (wave >> 2) * 32;        // 0 or 32  (M-split)
    const int wn = (wave & 3) * 128;        // 0..384   (N-split)
    const int fr = lane & 15;               // fragment row (A) / col (B)
    const int fs = lane >> 4;               // k-segment 0..3 (8 elems each)
    const size_t m0 = (size_t)blockIdx.x * BM;

    // A: lane reads x[row = m0+wm+mi*16+fr][k = kt*32 + fs*8 .. +7] (32B aligned)
    const float* ap0 = X + (m0 + wm + fr) * (size_t)KD + fs * 8;
    const float* ap1 = ap0 + (size_t)16 * KD;
    // B: lane reads H[row = wn+ni*16+fr][same k slice] (16B aligned, L2-hot)
    const __hip_bfloat16* bp[8];
#pragma unroll
    for (int ni = 0; ni < 8; ++ni)
        bp[ni] = Hm + (size_t)(wn + ni * 16 + fr) * KD + fs * 8;

    f32x4 acc[2][8];
#pragma unroll
    for (int i = 0; i < 2; ++i)
#pragma unroll
        for (int j = 0; j < 8; ++j) acc[i][j] = (f32x4)(0.f);

#pragma unroll 2
    for (int kt = 0; kt < KD / 32; ++kt) {
        const int ko = kt * 32;
        // issue HBM (A) loads first, then L2 (B) loads
        f32x4 a00 = *(const f32x4*)(ap0 + ko);
        f32x4 a01 = *(const f32x4*)(ap0 + ko + 4);
        f32x4 a10 = *(const f32x4*)(ap1 + ko);
        f32x4 a11 = *(const f32x4*)(ap1 + ko + 4);
        short8 bfr[8];
#pragma unroll
        for (int ni = 0; ni < 8; ++ni)
            bfr[ni] = *(const short8*)(bp[ni] + ko);
        short8 af0 = cvt_frag(a00, a01);
        short8 af1 = cvt_frag(a10, a11);
#pragma unroll
        for (int ni = 0; ni < 8; ++ni)
            acc[0][ni] = __builtin_amdgcn_mfma_f32_16x16x32_bf16(
                af0, bfr[ni], acc[0][ni], 0, 0, 0);
#pragma unroll
        for (int ni = 0; ni < 8; ++ni)
            acc[1][ni] = __builtin_amdgcn_mfma_f32_16x16x32_bf16(
                af1, bfr[ni], acc[1][ni], 0, 0, 0);
    }

    // ---- epilogue: C/D layout col = lane&15, row = (lane>>4)*4 + reg ----
    const int cm = wm + fs * 4;
#pragma unroll
    for (int mi = 0; mi < 2; ++mi) {
#pragma unroll
        for (int ni = 0; ni < 8; ++ni) {
            int col = wn + ni * 16 + fr;
            float bv = bias[col];
            float* op = out + (m0 + cm + mi * 16) * (size_t)ND + col;
#pragma unroll
            for (int r = 0; r < 4; ++r)
                op[(size_t)r * ND] = acc[mi][ni][r] + bv;
        }
    }
}

extern "C" void kernel_launch(void* const* d_in, const int* in_sizes, int n_in,
                              void* d_out, int out_size, void* d_ws, size_t ws_size,
                              hipStream_t stream) {
    const float* x    = (const float*)d_in[0];
    const float* A    = (const float*)d_in[1];
    const float* S    = (const float*)d_in[2];
    const float* bias = (const float*)d_in[3];
    float* out = (float*)d_out;
    __hip_bfloat16* H = (__hip_bfloat16*)d_ws;  // 512*512*2 = 512 KB scratch

    build_h<<<dim3(512 * 512 / 256), dim3(256), 0, stream>>>(A, S, H);
    phm_gemm<<<dim3(MDIM / BM), dim3(512), 0, stream>>>(x, H, bias, out);
}

// Round 2
// 475.064 us; speedup vs baseline: 1.4865x; 1.4865x over previous
//
#include <hip/hip_runtime.h>
#include <hip/hip_bf16.h>

// PHM8Linear: out[t, j] = sum_k H[j,k] * x[t,k] + bias[j]
//   H[j,k] = sum_i A[i, j>>6, k>>6] * S[i, j&63, k&63]   (512x512, bf16)
//   M = 16*8192 = 131072, K = N = 512.
// Memory floor: 268 MB x-read + 268 MB out-write ~= 85 us @ 6.3 TB/s.
//
// Structure: BN = 512 (full N per block) so each x row is fetched by exactly
// ONE block -> HBM FETCH == 268 MB by construction (round-0's 4-column grid
// re-fetched x 2x across XCD L2s). H (512 KB bf16) is L2-resident.
//
// H is stored k-major chunked: H2[(k>>3)*4096 + j*8 + (k&7)], so:
//   - global_load_lds staging is perfectly coalesced (lane i -> 16B at +16*i)
//   - the LDS tile is [fs][j][8]: 16 consecutive j-rows = 16 consecutive 16B
//     slots -> ds_read_b128 B-fragments are bank-conflict-free (round-0's
//     row-major B tile was an 8-way conflict, 12.6M conflict cycles).
// A (x, fp32) keeps round-0's XOR-swizzled row-major tile (proven pattern):
// LDS slot (row, c) holds global chunk c ^ (row&7).
//
// Block: 64 rows x 512 cols, 512 threads = 8 waves (2M x 4N), wave tile
// 32x128 -> acc[2][8] f32x4 = 64 AGPR. B-frags consumed in halves of 4 to
// keep unified regs <= 128 (__launch_bounds__(512,4) -> 2 blocks/CU so one
// block's barrier drain overlaps the other's compute).

#define MDIM (16 * 8192)
#define KD 512
#define ND 512
#define BM 64
#define BK 32

typedef __attribute__((ext_vector_type(8))) short short8;
typedef __attribute__((ext_vector_type(4))) float f32x4;

__device__ __forceinline__ unsigned pack2_bf16(float x, float y) {
    union { __hip_bfloat162 h; unsigned u; } cv;
    cv.h = __float22bfloat162_rn(make_float2(x, y));
    return cv.u;
}

__device__ __forceinline__ short8 cvt_frag(f32x4 a, f32x4 b) {
    union { unsigned u[4]; short8 s; } r;
    r.u[0] = pack2_bf16(a.x, a.y);
    r.u[1] = pack2_bf16(a.z, a.w);
    r.u[2] = pack2_bf16(b.x, b.y);
    r.u[3] = pack2_bf16(b.z, b.w);
    return r.s;
}

__device__ __forceinline__ void async16(const void* g, void* l) {
    __builtin_amdgcn_global_load_lds(
        (const __attribute__((address_space(1))) unsigned*)g,
        (__attribute__((address_space(3))) unsigned*)l, 16, 0, 0);
}

// H2 chunk (j, kc) = H[j][kc*8 .. kc*8+7] stored at element offset kc*4096+j*8.
// One thread computes one 8-wide chunk -> coalesced 16B stores.
__global__ void build_h(const float* __restrict__ A, const float* __restrict__ S,
                        __hip_bfloat16* __restrict__ H2) {
    int idx = blockIdx.x * 256 + threadIdx.x;   // 0 .. 32767 = kc*512 + j
    int j = idx & 511, kc = idx >> 9;
    int a = j >> 6, b = j & 63, c = kc >> 3, d0 = (kc & 7) * 8;
    float acc[8];
#pragma unroll
    for (int kk = 0; kk < 8; ++kk) acc[kk] = 0.f;
#pragma unroll
    for (int i = 0; i < 8; ++i) {
        float av = A[i * 64 + a * 8 + c];
        const float* sp = S + i * 4096 + b * 64 + d0;
#pragma unroll
        for (int kk = 0; kk < 8; ++kk) acc[kk] += av * sp[kk];
    }
    union { unsigned u[4]; short8 s; } r;
    r.u[0] = pack2_bf16(acc[0], acc[1]);
    r.u[1] = pack2_bf16(acc[2], acc[3]);
    r.u[2] = pack2_bf16(acc[4], acc[5]);
    r.u[3] = pack2_bf16(acc[6], acc[7]);
    *(short8*)(H2 + (size_t)idx * 8) = r.s;
}

__global__ __launch_bounds__(512, 4)
void phm_gemm(const float* __restrict__ X, const __hip_bfloat16* __restrict__ Hm,
              const float* __restrict__ bias, float* __restrict__ out) {
    __shared__ __attribute__((aligned(16))) float As[BM * BK];            // 8 KB
    __shared__ __attribute__((aligned(16))) __hip_bfloat16 Bs[4 * ND * 8]; // 32 KB

    const int tid = threadIdx.x;
    const int wave = tid >> 6, lane = tid & 63;
    const int wm = (wave >> 2) * 32;        // 0 / 32
    const int wn = (wave & 3) * 128;        // 0..384
    const int fr = lane & 15;
    const int fs = lane >> 4;
    const size_t m0 = (size_t)blockIdx.x * BM;

    // A staging: 512 chunks of 16B; thread tid -> row = tid>>3, lds col = tid&7,
    // global col = (tid&7) ^ (row&7)  (XOR swizzle; dest linear as required).
    const int ar = tid >> 3;
    const int acg = (tid & 7) ^ (ar & 7);
    const float* ag = X + (m0 + ar) * (size_t)KD + acg * 4;
    void* al = (char*)As + tid * 16;
    // B staging: q=0..3: global chunk (j=tid, kc=kt*4+q) -> LDS slot q*512+tid.
    const __hip_bfloat16* bg = Hm + (size_t)tid * 8;

    // fragment read bases
    const float* arp = As + (wm + fr) * BK;
    const int ca = (2 * fs) ^ (fr & 7);
    const __hip_bfloat16* brp = Bs + ((size_t)fs * ND + wn + fr) * 8;

    f32x4 acc[2][8];
#pragma unroll
    for (int i = 0; i < 2; ++i)
#pragma unroll
        for (int j = 0; j < 8; ++j) acc[i][j] = (f32x4)(0.f);

#pragma unroll 1
    for (int kt = 0; kt < KD / BK; ++kt) {
        async16(ag + kt * BK, al);
#pragma unroll
        for (int q = 0; q < 4; ++q)
            async16(bg + (size_t)(kt * 4 + q) * (ND * 8),
                    (char*)Bs + q * 8192 + tid * 16);
        __syncthreads();   // vmcnt(0) drain emitted by compiler

        short8 af[2];
#pragma unroll
        for (int mi = 0; mi < 2; ++mi) {
            const float* rp = arp + mi * 16 * BK;
            f32x4 a0 = *(const f32x4*)(rp + ca * 4);
            f32x4 a1 = *(const f32x4*)(rp + (ca ^ 1) * 4);
            af[mi] = cvt_frag(a0, a1);
        }
#pragma unroll
        for (int h = 0; h < 2; ++h) {
            short8 bfr[4];
#pragma unroll
            for (int ni = 0; ni < 4; ++ni)
                bfr[ni] = *(const short8*)(brp + (h * 4 + ni) * 128);
#pragma unroll
            for (int mi = 0; mi < 2; ++mi)
#pragma unroll
                for (int ni = 0; ni < 4; ++ni)
                    acc[mi][h * 4 + ni] = __builtin_amdgcn_mfma_f32_16x16x32_bf16(
                        af[mi], bfr[ni], acc[mi][h * 4 + ni], 0, 0, 0);
        }
        __syncthreads();
    }

    // ---- epilogue: C/D layout col = lane&15, row = (lane>>4)*4 + reg ----
    const int cm = wm + fs * 4;
#pragma unroll
    for (int mi = 0; mi < 2; ++mi) {
#pragma unroll
        for (int ni = 0; ni < 8; ++ni) {
            int col = wn + ni * 16 + fr;
            float bv = bias[col];
            float* op = out + (m0 + cm + mi * 16) * (size_t)ND + col;
#pragma unroll
            for (int r = 0; r < 4; ++r)
                op[(size_t)r * ND] = acc[mi][ni][r] + bv;
        }
    }
}

extern "C" void kernel_launch(void* const* d_in, const int* in_sizes, int n_in,
                              void* d_out, int out_size, void* d_ws, size_t ws_size,
                              hipStream_t stream) {
    const float* x    = (const float*)d_in[0];
    const float* A    = (const float*)d_in[1];
    const float* S    = (const float*)d_in[2];
    const float* bias = (const float*)d_in[3];
    float* out = (float*)d_out;
    __hip_bfloat16* H = (__hip_bfloat16*)d_ws;  // 512*512*2 = 512 KB scratch

    build_h<<<dim3(512 * 64 / 256), dim3(256), 0, stream>>>(A, S, H);
    phm_gemm<<<dim3(MDIM / BM), dim3(512), 0, stream>>>(x, H, bias, out);
}